// Round 2
// baseline (2119.908 us; speedup 1.0000x reference)
//
#include <hip/hip_runtime.h>

#define N_NODES   50000
#define N_EDGES   800000
#define N_GRAPHS  256
#define EMB       128
#define L_LAYERS  8
#define N_CLASSES 10
#define BN_EPS    1e-5f
#define NEG_SLOPE 0.01f
#define BM 64
#define NBLK ((N_NODES + BM - 1) / BM)   // 782 mlp blocks

// ---------------------------------------------------------------------------
// CSR build
// ---------------------------------------------------------------------------
__global__ void deg_kernel(const int* __restrict__ ei, int* __restrict__ deg) {
    int e = blockIdx.x * 256 + threadIdx.x;
    if (e < N_EDGES) atomicAdd(&deg[ei[N_EDGES + e]], 1);
}

__global__ void scan_kernel(const int* __restrict__ deg,
                            int* __restrict__ rowptr, int* __restrict__ cursor) {
    __shared__ int sums[256];
    __shared__ int offs[257];
    int t = threadIdx.x;
    const int chunk = (N_NODES + 255) / 256;  // 196
    int start = t * chunk;
    int end   = start + chunk; if (end > N_NODES) end = N_NODES;
    int s = 0;
    for (int i = start; i < end; ++i) s += deg[i];
    sums[t] = s;
    __syncthreads();
    if (t == 0) {
        int a = 0;
        for (int i = 0; i < 256; ++i) { offs[i] = a; a += sums[i]; }
        offs[256] = a;
    }
    __syncthreads();
    int a = offs[t];
    for (int i = start; i < end; ++i) {
        rowptr[i] = a; cursor[i] = a; a += deg[i];
    }
    if (t == 255) rowptr[N_NODES] = offs[256];
}

__global__ void scatter_kernel(const int* __restrict__ ei,
                               int* __restrict__ cursor, int* __restrict__ csr) {
    int e = blockIdx.x * 256 + threadIdx.x;
    if (e < N_EDGES) {
        int d = ei[N_EDGES + e];
        int s = ei[e];
        int p = atomicAdd(&cursor[d], 1);
        csr[p] = s;
    }
}

// Deterministic adjacency: sort each node's neighbor list.
__global__ void sort_adj_kernel(const int* __restrict__ rowptr, int* __restrict__ csr) {
    int node = blockIdx.x * 256 + threadIdx.x;
    if (node >= N_NODES) return;
    int beg = rowptr[node];
    int end = rowptr[node + 1];
    for (int i = beg + 1; i < end; ++i) {
        int v = csr[i];
        int j = i - 1;
        while (j >= beg && csr[j] > v) { csr[j + 1] = csr[j]; --j; }
        csr[j + 1] = v;
    }
}

// ---------------------------------------------------------------------------
// GIN aggregate: hpre[i] = x[i] + sum_{j->i} x[j]  (deterministic csr order,
// sequential adds preserved bitwise; unroll-4 widens the load window)
// ---------------------------------------------------------------------------
__global__ __launch_bounds__(256) void agg_kernel(
        const float* __restrict__ x, const int* __restrict__ rowptr,
        const int* __restrict__ csr, float* __restrict__ hpre) {
    int lane = threadIdx.x & 63;
    int node = __builtin_amdgcn_readfirstlane(blockIdx.x * 4 + (threadIdx.x >> 6));
    if (node >= N_NODES) return;
    int beg = rowptr[node];
    int end = rowptr[node + 1];
    const float2* xp = (const float2*)x;
    float2 acc = xp[(size_t)node * 64 + lane];
    int e = beg;
    for (; e + 3 < end; e += 4) {
        int s0 = csr[e];
        int s1 = csr[e + 1];
        int s2 = csr[e + 2];
        int s3 = csr[e + 3];
        float2 v0 = xp[(size_t)s0 * 64 + lane];
        float2 v1 = xp[(size_t)s1 * 64 + lane];
        float2 v2 = xp[(size_t)s2 * 64 + lane];
        float2 v3 = xp[(size_t)s3 * 64 + lane];
        acc.x += v0.x; acc.y += v0.y;   // keep exact sequential order
        acc.x += v1.x; acc.y += v1.y;
        acc.x += v2.x; acc.y += v2.y;
        acc.x += v3.x; acc.y += v3.y;
    }
    for (; e < end; ++e) {
        int s0 = csr[e];
        float2 v0 = xp[(size_t)s0 * 64 + lane];
        acc.x += v0.x; acc.y += v0.y;
    }
    ((float2*)hpre)[(size_t)node * 64 + lane] = acc;
}

// ---------------------------------------------------------------------------
// Fused MLP, 8x8 register tiles.
// A (and mid-tile T) live in LDS column-major [k][r] with a 4-float-granule
// XOR swizzle: elem (k,r) at  k*64 + (r&3) + 4*((r>>2) ^ (k&15)).
// -> all inner-loop LDS reads are 16B-aligned ds_read_b128, 2-way (free).
// Accumulation order per output is strict k=0..127 (bitwise-identical to the
// previous version); BN partials keep the old 16-groups-of-4-rows order.
// ---------------------------------------------------------------------------
#define ROWF(i, av)                                                    \
    acc[i][0] += (av) * b0.x;  acc[i][1] += (av) * b0.y;               \
    acc[i][2] += (av) * b0.z;  acc[i][3] += (av) * b0.w;               \
    acc[i][4] += (av) * b1v.x; acc[i][5] += (av) * b1v.y;              \
    acc[i][6] += (av) * b1v.z; acc[i][7] += (av) * b1v.w;

#define MAC_K(KBASE, K2C, SWAP)                                        \
    {                                                                  \
        const int k2c = (K2C);                                         \
        int gb = tr2 ^ (k2c & 14);                                     \
        const float4* ap =                                             \
            (const float4*)&AsT[((KBASE) + k2c) * 64 + gb * 4];        \
        float4 aA = ap[0];                                             \
        float4 aB = ap[1];                                             \
        if (SWAP) { float4 tq = aA; aA = aB; aB = tq; }                \
        const float4* bp = (const float4*)&Ws[k2c * 128 + tc * 8];     \
        float4 b0  = bp[0];                                            \
        float4 b1v = bp[1];                                            \
        ROWF(0, aA.x) ROWF(1, aA.y) ROWF(2, aA.z) ROWF(3, aA.w)        \
        ROWF(4, aB.x) ROWF(5, aB.y) ROWF(6, aB.z) ROWF(7, aB.w)        \
    }

__device__ __forceinline__ void gemm_phase(
        const float* __restrict__ W, const float* AsT, float* Ws,
        int t, int tr2, int tc, float (&acc)[8][8]) {
    for (int kk = 0; kk < 128; kk += 32) {
        __syncthreads();
        const float4* Wg = (const float4*)(W + kk * 128);
        #pragma unroll
        for (int rep = 0; rep < 8; ++rep) {
            int v = t + rep * 128;
            ((float4*)Ws)[v] = Wg[v];
        }
        __syncthreads();
        #pragma unroll 8
        for (int k2 = 0; k2 < 32; k2 += 2) {
            MAC_K(kk, k2, false)
            MAC_K(kk, k2 + 1, true)
        }
    }
}

__global__ __launch_bounds__(128) void mlp_kernel(
        float* __restrict__ HB,
        const float* __restrict__ W1, const float* __restrict__ b1,
        const float* __restrict__ W2, const float* __restrict__ b2,
        float* __restrict__ pstat) {
    __shared__ float AsT[128 * 64];   // 32 KB: transposed+swizzled A / T tile
    __shared__ float Ws[32 * 128];    // 16 KB: W chunk, reused for stats

    const int t   = threadIdx.x;      // 0..127
    const int tr  = t & 7;            // rows 8*tr .. 8*tr+7
    const int tc  = t >> 3;           // cols 8*tc .. 8*tc+7   (0..15)
    const int tr2 = tr * 2;
    const int row0 = blockIdx.x * BM;

    // ---- stage A: global (row-major) -> LDS (col-major, swizzled) ----
    {
        const float4* Ag = (const float4*)HB;
        #pragma unroll
        for (int rep = 0; rep < 16; ++rep) {
            int v  = t + rep * 128;
            int r  = v >> 5;           // 0..63
            int c4 = v & 31;
            int gr = row0 + r;
            float4 val = (gr < N_NODES) ? Ag[(size_t)gr * 32 + c4]
                                        : make_float4(0.f, 0.f, 0.f, 0.f);
            int rl = r & 3;
            int rh = r >> 2;
            int k0 = c4 * 4;
            AsT[(k0 + 0) * 64 + rl + 4 * (rh ^ ((k0 + 0) & 15))] = val.x;
            AsT[(k0 + 1) * 64 + rl + 4 * (rh ^ ((k0 + 1) & 15))] = val.y;
            AsT[(k0 + 2) * 64 + rl + 4 * (rh ^ ((k0 + 2) & 15))] = val.z;
            AsT[(k0 + 3) * 64 + rl + 4 * (rh ^ ((k0 + 3) & 15))] = val.w;
        }
    }

    float acc[8][8];
    #pragma unroll
    for (int i = 0; i < 8; ++i)
        #pragma unroll
        for (int j = 0; j < 8; ++j) acc[i][j] = 0.f;

    // phase 1: T = leaky(A @ W1 + b1)
    gemm_phase(W1, AsT, Ws, t, tr2, tc, acc);

    // ---- transform: bias + leaky, write T back transposed+swizzled ----
    __syncthreads();   // all phase-1 reads of AsT done
    #pragma unroll
    for (int j = 0; j < 8; ++j) {
        int c = tc * 8 + j;            // = kT for phase 2
        float bias = b1[c];
        float v0 = acc[0][j] + bias, v1 = acc[1][j] + bias;
        float v2 = acc[2][j] + bias, v3 = acc[3][j] + bias;
        float v4 = acc[4][j] + bias, v5 = acc[5][j] + bias;
        float v6 = acc[6][j] + bias, v7 = acc[7][j] + bias;
        v0 = (v0 > 0.f) ? v0 : NEG_SLOPE * v0;
        v1 = (v1 > 0.f) ? v1 : NEG_SLOPE * v1;
        v2 = (v2 > 0.f) ? v2 : NEG_SLOPE * v2;
        v3 = (v3 > 0.f) ? v3 : NEG_SLOPE * v3;
        v4 = (v4 > 0.f) ? v4 : NEG_SLOPE * v4;
        v5 = (v5 > 0.f) ? v5 : NEG_SLOPE * v5;
        v6 = (v6 > 0.f) ? v6 : NEG_SLOPE * v6;
        v7 = (v7 > 0.f) ? v7 : NEG_SLOPE * v7;
        float4 lo = make_float4(v0, v1, v2, v3);
        float4 hi = make_float4(v4, v5, v6, v7);
        float4 w0 = (j & 1) ? hi : lo;   // compile-time select
        float4 w1 = (j & 1) ? lo : hi;
        int gb = tr2 ^ (8 * (tc & 1)) ^ (j & 14);
        *(float4*)&AsT[c * 64 + gb * 4]     = w0;
        *(float4*)&AsT[c * 64 + gb * 4 + 4] = w1;
        #pragma unroll
        for (int i = 0; i < 8; ++i) acc[i][j] = 0.f;
    }

    // phase 2: H = T @ W2 + b2   (first sync inside gemm_phase covers T-writes)
    gemm_phase(W2, AsT, Ws, t, tr2, tc, acc);

    // ---- epilogue: bias, store H, per-group(4-row) BN partials ----
    float gs[2][8], gq[2][8];
    #pragma unroll
    for (int h = 0; h < 2; ++h)
        #pragma unroll
        for (int j = 0; j < 8; ++j) { gs[h][j] = 0.f; gq[h][j] = 0.f; }

    #pragma unroll
    for (int i = 0; i < 8; ++i) {
        int gr = row0 + tr * 8 + i;
        if (gr < N_NODES) {
            float tmp[8];
            #pragma unroll
            for (int j = 0; j < 8; ++j) {
                float v = acc[i][j] + b2[tc * 8 + j];
                tmp[j] = v;
                gs[i >> 2][j] += v;       // rows ascending within group of 4
                gq[i >> 2][j] += v * v;
            }
            float4 o0 = make_float4(tmp[0], tmp[1], tmp[2], tmp[3]);
            float4 o1 = make_float4(tmp[4], tmp[5], tmp[6], tmp[7]);
            *(float4*)&HB[(size_t)gr * EMB + tc * 8]     = o0;
            *(float4*)&HB[(size_t)gr * EMB + tc * 8 + 4] = o1;
        }
    }

    __syncthreads();                 // done reading Ws (phase 2)
    float2* red2 = (float2*)Ws;      // [16 groups][128 cols]
    #pragma unroll
    for (int h = 0; h < 2; ++h)
        #pragma unroll
        for (int j = 0; j < 8; ++j) {
            float2 p; p.x = gs[h][j]; p.y = gq[h][j];
            red2[(tr * 2 + h) * 128 + tc * 8 + j] = p;
        }
    __syncthreads();
    {
        float s = 0.f, q = 0.f;
        #pragma unroll
        for (int g = 0; g < 16; ++g) {   // ascending group order (as before)
            float2 p = red2[g * 128 + t];
            s += p.x; q += p.y;
        }
        float2 o; o.x = s; o.y = q;
        *(float2*)&pstat[(size_t)blockIdx.x * 256 + 2 * t] = o;
    }
}

// Fixed-order reduction of per-block partials -> mu / inv
// (same sequential order b=0..781; unroll only widens the load window)
__global__ __launch_bounds__(128) void bn_stats_kernel(
        const float* __restrict__ pstat,
        float* __restrict__ mu_out, float* __restrict__ inv_out) {
    int t = threadIdx.x;
    float s = 0.f, q = 0.f;
    const float2* p = (const float2*)pstat;  // [b][128] float2
    int b = 0;
    for (; b + 4 <= NBLK; b += 4) {
        float2 v0 = p[(size_t)(b + 0) * 128 + t];
        float2 v1 = p[(size_t)(b + 1) * 128 + t];
        float2 v2 = p[(size_t)(b + 2) * 128 + t];
        float2 v3 = p[(size_t)(b + 3) * 128 + t];
        s += v0.x; q += v0.y;
        s += v1.x; q += v1.y;
        s += v2.x; q += v2.y;
        s += v3.x; q += v3.y;
    }
    for (; b < NBLK; ++b) {
        float2 v = p[(size_t)b * 128 + t];
        s += v.x; q += v.y;
    }
    const float invN = 1.f / (float)N_NODES;
    float mu  = s * invN;
    float var = q * invN - mu * mu;
    mu_out[t]  = mu;
    inv_out[t] = rsqrtf(var + BN_EPS);
}

// ---------------------------------------------------------------------------
// BatchNorm + gumbel-argmax one-hot + graph max + next-x
// wave-per-node: 2 features/lane, shuffle-butterfly argmax, no LDS/syncs
// ---------------------------------------------------------------------------
__global__ __launch_bounds__(256) void finalize_kernel(
        const float* __restrict__ h,
        const float* __restrict__ mu_v, const float* __restrict__ inv_v,
        const float* __restrict__ gamma, const float* __restrict__ beta,
        const float* __restrict__ gumbel_l, const int* __restrict__ batch,
        float* __restrict__ nc_out, float* __restrict__ gc_out,
        float* __restrict__ xnext) {
    int lane = threadIdx.x & 63;
    int node = blockIdx.x * 4 + (threadIdx.x >> 6);

    float2 hv  = ((const float2*)h)[(size_t)node * 64 + lane];
    float2 mu2 = ((const float2*)mu_v)[lane];
    float2 iv2 = ((const float2*)inv_v)[lane];
    float2 g2  = ((const float2*)gamma)[lane];
    float2 be2 = ((const float2*)beta)[lane];
    float2 gm  = ((const float2*)gumbel_l)[(size_t)node * 64 + lane];

    float hb0 = (hv.x - mu2.x) * iv2.x * g2.x + be2.x;
    float hb1 = (hv.y - mu2.y) * iv2.y * g2.y + be2.y;
    float y0 = hb0 + gm.x;   // TAU == 1.0
    float y1 = hb1 + gm.y;

    float bv; int bi;
    if (y1 > y0) { bv = y1; bi = 2 * lane + 1; }
    else         { bv = y0; bi = 2 * lane; }
    #pragma unroll
    for (int off = 32; off > 0; off >>= 1) {
        float ov = __shfl_xor(bv, off);
        int   oi = __shfl_xor(bi, off);
        if (ov > bv || (ov == bv && oi < bi)) { bv = ov; bi = oi; }
    }

    float2 nc;
    nc.x = (bi == 2 * lane)     ? 1.0f : 0.0f;
    nc.y = (bi == 2 * lane + 1) ? 1.0f : 0.0f;
    ((float2*)nc_out)[(size_t)node * 64 + lane] = nc;

    float2 xn;
    xn.x = (hb0 > 0.f) ? hb0 : NEG_SLOPE * hb0;
    xn.y = (hb1 > 0.f) ? hb1 : NEG_SLOPE * hb1;
    ((float2*)xnext)[(size_t)node * 64 + lane] = xn;

    // device-scope atomic: cross-XCD-safe idempotent write
    if (lane == 0) atomicExch(&gc_out[(size_t)batch[node] * EMB + bi], 1.0f);
}

// ---------------------------------------------------------------------------
// logits = gc_last @ dense_W + dense_b
// ---------------------------------------------------------------------------
__global__ __launch_bounds__(128) void logits_kernel(
        const float* __restrict__ gc, const float* __restrict__ W,
        const float* __restrict__ b, float* __restrict__ out) {
    __shared__ float row[EMB];
    int g = blockIdx.x;
    int t = threadIdx.x;
    row[t] = gc[g * EMB + t];
    __syncthreads();
    if (t < N_CLASSES) {
        float acc = b[t];
        for (int k = 0; k < EMB; ++k) acc += row[k] * W[k * N_CLASSES + t];
        out[g * N_CLASSES + t] = acc;
    }
}

// ---------------------------------------------------------------------------
extern "C" void kernel_launch(void* const* d_in, const int* in_sizes, int n_in,
                              void* d_out, int out_size, void* d_ws, size_t ws_size,
                              hipStream_t stream) {
    const float* x_in    = (const float*)d_in[0];
    const int*   ei      = (const int*)  d_in[1];
    const int*   batch   = (const int*)  d_in[2];
    const float* W1      = (const float*)d_in[3];
    const float* b1      = (const float*)d_in[4];
    const float* W2      = (const float*)d_in[5];
    const float* b2      = (const float*)d_in[6];
    const float* gamma   = (const float*)d_in[7];
    const float* beta    = (const float*)d_in[8];
    const float* gumbel  = (const float*)d_in[9];
    const float* dW      = (const float*)d_in[10];
    const float* db      = (const float*)d_in[11];

    float* out = (float*)d_out;
    const size_t NC_OFF = (size_t)N_GRAPHS * N_CLASSES;
    const size_t GC_OFF = NC_OFF + (size_t)L_LAYERS * N_NODES * EMB;
    float* logits_out = out;
    float* nc_out     = out + NC_OFF;
    float* gc_out     = out + GC_OFF;

    // workspace layout
    float* xbuf    = (float*)d_ws;                    // 6.4M floats
    float* hbuf    = xbuf + (size_t)N_NODES * EMB;    // 6.4M floats
    float* pstat   = hbuf + (size_t)N_NODES * EMB;    // NBLK*256 (sum/sq interleaved)
    float* mu_v    = pstat + (size_t)NBLK * 256;      // 128
    float* inv_v   = mu_v + EMB;                      // 128
    int*   rowptr  = (int*)(inv_v + EMB);             // 50001
    int*   cursor  = rowptr + (N_NODES + 1);          // 50000
    int*   csr     = cursor + N_NODES;                // 800000
    int*   deg     = csr + N_EDGES;                   // 50000

    // CSR build (deterministic after per-node sort)
    hipMemsetAsync(deg, 0, N_NODES * sizeof(int), stream);
    deg_kernel<<<(N_EDGES + 255) / 256, 256, 0, stream>>>(ei, deg);
    scan_kernel<<<1, 256, 0, stream>>>(deg, rowptr, cursor);
    scatter_kernel<<<(N_EDGES + 255) / 256, 256, 0, stream>>>(ei, cursor, csr);
    sort_adj_kernel<<<(N_NODES + 255) / 256, 256, 0, stream>>>(rowptr, csr);

    hipMemsetAsync(gc_out, 0,
                   (size_t)L_LAYERS * N_GRAPHS * EMB * sizeof(float), stream);

    for (int l = 0; l < L_LAYERS; ++l) {
        const float* xsrc = (l == 0) ? x_in : xbuf;
        agg_kernel<<<(N_NODES + 3) / 4, 256, 0, stream>>>(xsrc, rowptr, csr, hbuf);
        mlp_kernel<<<NBLK, 128, 0, stream>>>(
            hbuf,
            W1 + (size_t)l * EMB * EMB, b1 + (size_t)l * EMB,
            W2 + (size_t)l * EMB * EMB, b2 + (size_t)l * EMB,
            pstat);
        bn_stats_kernel<<<1, 128, 0, stream>>>(pstat, mu_v, inv_v);
        finalize_kernel<<<(N_NODES + 3) / 4, 256, 0, stream>>>(
            hbuf, mu_v, inv_v,
            gamma + (size_t)l * EMB, beta + (size_t)l * EMB,
            gumbel + (size_t)l * N_NODES * EMB, batch,
            nc_out + (size_t)l * N_NODES * EMB,
            gc_out + (size_t)l * N_GRAPHS * EMB,
            xbuf);
    }

    logits_kernel<<<N_GRAPHS, 128, 0, stream>>>(
        gc_out + (size_t)(L_LAYERS - 1) * N_GRAPHS * EMB, dW, db, logits_out);
}